// Round 26
// baseline (112.504 us; speedup 1.0000x reference)
//
#include <hip/hip_runtime.h>

#define NN 10000
#define NE 160000
#define KD 1433
#define KP 1536    // padded K (zero-filled in Wb)
#define SK1 2      // split-K partial buffers (unchanged for consumers)
#define KC 768     // K per block
#define KSTEP 64   // K per LDS stage
#define NST 12     // KC/KSTEP
#define MAXD 64    // slot-CSR bucket size (P(deg>64) ~ 1e-12, clamped)

typedef unsigned short u16;
typedef __attribute__((ext_vector_type(4))) float f32x4;
typedef __attribute__((ext_vector_type(8))) short bf16x8;
typedef __attribute__((ext_vector_type(4), aligned(4))) float f32x4u;

__device__ __forceinline__ u16 f2bf(float f) {
    union { float f; unsigned u; } v; v.f = f;
    unsigned r = (v.u + 0x7FFF + ((v.u >> 16) & 1)) >> 16;
    return (u16)r;
}
__device__ __forceinline__ float b2f(u16 u) {
    union { unsigned u; float f; } v; v.u = ((unsigned)u) << 16;
    return v.f;
}

__device__ __forceinline__ void gload16(const void* g, void* l) {
    __builtin_amdgcn_global_load_lds(
        (__attribute__((address_space(1))) void*)(void*)g,
        (__attribute__((address_space(3))) void*)l, 16, 0, 0);
}

// ---------- prep: edges repack + slot-CSR scatter + degree | convw | MLP collapse ----------
__global__ __launch_bounds__(256) void prep_kernel(const int* __restrict__ e,
                                                   int* __restrict__ cnt, int* __restrict__ csr,
                                                   const float* __restrict__ Wl, const float* __restrict__ Wr,
                                                   u16* __restrict__ Wb,
                                                   const float* __restrict__ M1w, const float* __restrict__ M1b,
                                                   const float* __restrict__ M2w, const float* __restrict__ M2b,
                                                   float* __restrict__ Mc, float* __restrict__ bc) {
    const int b = blockIdx.x, t = threadIdx.x;
    if (b < 625) {
        __shared__ int nzs;
        if (t == 0) nzs = 0;
        __syncthreads();
        int i = b * 256 + t;
        int hv = (i < NE) ? e[2 * i + 1] : 0;
        if (hv) nzs = 1;   // benign race
        __syncthreads();
        if (i < NE) {
            int s, d;
            if (nzs == 0) { s = e[2 * i]; d = e[2 * (NE + i)]; }
            else          { s = e[i];     d = e[NE + i]; }
            int pos = atomicAdd(&cnt[d], 1);
            if (pos < MAXD) csr[d * MAXD + pos] = s;
        }
    } else if (b < 721) {
        int gid = (b - 625) * 256 + t;
        int r = gid / (KP / 8), k0 = (gid % (KP / 8)) * 8;
        const float* srcw = (r < 64) ? (Wl + r * KD) : (Wr + (r - 64) * KD);
        u16 u[8];
        #pragma unroll
        for (int i = 0; i < 8; ++i) {
            int k = k0 + i;
            u[i] = (k < KD) ? f2bf(srcw[k]) : (u16)0;
        }
        *(uint4*)&Wb[r * KP + k0] = *(const uint4*)u;
    } else {
        if (t < 224) {
            int c = t >> 5, d = t & 31;
            float acc = 0.f;
            for (int k = 0; k < 32; ++k)
                acc += M2w[c * 32 + k] * M1w[k * 32 + d];
            Mc[t] = acc;
        } else if (t < 232) {
            Mc[t] = 0.f;
            int c = t - 224;
            if (c < 7) {
                float acc = M2b[c];
                for (int k = 0; k < 32; ++k)
                    acc += M2w[c * 32 + k] * M1b[k];
                bc[c] = acc;
            } else bc[7] = 0.f;
        } else Mc[t] = 0.f;
    }
}

// ---------- layer-1 MFMA GEMM v7: col-split grid (313,4), 32KB LDS, 5 blocks/CU ----------
// blockIdx.y = ky*2 + ch: ky = K-half (partial buffer), ch = column half (64 cols).
__global__ __launch_bounds__(256) void mm1_mfma(const float* __restrict__ x, const u16* __restrict__ Wb,
                                                u16* __restrict__ ypu) {
    __shared__ float AT[2][2048];   // 8KB/buf: 32 rows x 64 fp32
    __shared__ u16  WT[2][4096];    // 8KB/buf: 64 rows x 64 bf16
    const int t = threadIdx.x;
    const int w = t >> 6, lane = t & 63;
    const int n0 = blockIdx.x * 32;
    const int ky = blockIdx.y >> 1;
    const int ch = blockIdx.y & 1;
    const int kc0 = ky * KC;

    // A staging (unchanged): wave w stages pages 2w, 2w+1 (4 rows each)
    const int rowinA = lane >> 4;
    const int cA = lane & 15;
    size_t aoff[2];
    #pragma unroll
    for (int ii = 0; ii < 2; ++ii) {
        int i = 2 * w + ii;
        int r = 4 * i + rowinA;
        int grow = n0 + r; if (grow >= NN) grow = NN - 1;
        int q = cA ^ (rowinA << 2) ^ (i & 3);
        aoff[ii] = (size_t)grow * KD + (size_t)kc0 + (size_t)(q * 4);
    }
    const size_t amax = (size_t)NN * KD - 4;

    // W staging: 64-row strip (rows ch*64 .. ch*64+63); wave w stages pages 2w, 2w+1 (8 rows each)
    const int rowinW = lane >> 3;
    const int qw = (lane & 7) ^ rowinW;
    size_t woff[2];
    #pragma unroll
    for (int jj = 0; jj < 2; ++jj) {
        int j = 2 * w + jj;
        int r = ch * 64 + 8 * j + rowinW;
        woff[jj] = (size_t)r * KP + (size_t)kc0 + (size_t)(qw * 8);
    }

    // fragments: wave = (row-half w&1) x (col-quarter w>>1); 16 rows x 32 cols per wave
    const int fr = lane & 15, hi = lane >> 4;
    const int ar0 = (w & 1) * 16;
    const int cw = (w >> 1) * 32;          // local col base within 64-col strip
    const int arow = ar0 + fr;
    const int apage = (arow >> 2) * 256 + (arow & 3) * 64;
    const int asw = ((arow & 3) << 2) ^ ((arow >> 2) & 3);

    f32x4 acc[2] = {};

    auto stage = [&](int s, int bb) {
        const int ko = s * KSTEP;
        #pragma unroll
        for (int ii = 0; ii < 2; ++ii) {
            size_t o = aoff[ii] + ko;
            if (o > amax) o = amax;
            gload16(x + o, &AT[bb][(2 * w + ii) * 256]);
        }
        #pragma unroll
        for (int jj = 0; jj < 2; ++jj)
            gload16(Wb + woff[jj] + ko, &WT[bb][(2 * w + jj) * 512]);
    };

    // 2-deep prologue: 8 loads/wave in flight
    stage(0, 0);
    stage(1, 1);

    for (int s = 0; s < NST; ++s) {
        if (s + 1 < NST) {
            asm volatile("s_waitcnt vmcnt(4)" ::: "memory");   // drain stage s; stage s+1 stays in flight
        } else {
            asm volatile("s_waitcnt vmcnt(0)" ::: "memory");
        }
        __builtin_amdgcn_sched_barrier(0);
        __builtin_amdgcn_s_barrier();
        __builtin_amdgcn_sched_barrier(0);

        const float* ab = &AT[s & 1][0];
        const u16* wbuf = &WT[s & 1][0];
        #pragma unroll
        for (int p = 0; p < 2; ++p) {
            const int q0 = p * 8 + hi * 2;
            f32x4 alo = *(const f32x4*)&ab[apage + ((q0    ) ^ asw) * 4];
            f32x4 ahi = *(const f32x4*)&ab[apage + ((q0 + 1) ^ asw) * 4];
            u16 au[8] = { f2bf(alo[0]), f2bf(alo[1]), f2bf(alo[2]), f2bf(alo[3]),
                          f2bf(ahi[0]), f2bf(ahi[1]), f2bf(ahi[2]), f2bf(ahi[3]) };
            bf16x8 af = *(const bf16x8*)au;
            #pragma unroll
            for (int f = 0; f < 2; ++f) {
                int lr = cw + f * 16 + fr;                     // local W row 0..63
                int kcw = (p * 4 + hi) ^ (lr & 7);
                bf16x8 bfr = *(const bf16x8*)&wbuf[(lr >> 3) * 512 + (lr & 7) * 64 + kcw * 8];
                acc[f] = __builtin_amdgcn_mfma_f32_16x16x32_bf16(af, bfr, acc[f], 0, 0, 0);
            }
        }

        __builtin_amdgcn_sched_barrier(0);
        __builtin_amdgcn_s_barrier();
        __builtin_amdgcn_sched_barrier(0);
        if (s + 2 < NST) stage(s + 2, s & 1);
    }

    u16* ypb = ypu + (size_t)ky * NN * 128;
    #pragma unroll
    for (int f = 0; f < 2; ++f) {
        #pragma unroll
        for (int j = 0; j < 4; ++j) {
            int n = n0 + ar0 + hi * 4 + j;
            int col = ch * 64 + cw + f * 16 + fr;
            if (n < NN) ypb[n * 128 + col] = f2bf(acc[f][j]);
        }
    }
}

// ---------- layer1 fused: bf16 gather(yp0+yp1) + combine + GEMM ----------
__global__ __launch_bounds__(256) void layer1_fused(const u16* __restrict__ ypu, const int* __restrict__ csr,
                                                    const int* __restrict__ cnt,
                                                    const float* __restrict__ b,
                                                    const float* __restrict__ Wl, const float* __restrict__ Wr,
                                                    float* __restrict__ yout) {
    __shared__ float Xs[4][65];
    __shared__ float Ws[64][65];
    const int t = threadIdx.x;
    const int w = t >> 6, lane = t & 63;
    const int n0 = blockIdx.x * 4;
    const u16* yp1 = ypu + (size_t)NN * 128;

    #pragma unroll
    for (int i = 0; i < 16; ++i) {
        int e2 = t + i * 256;
        int row = e2 >> 6, col = e2 & 63;
        Ws[row][col] = (row < 32) ? Wl[row * 64 + col] : Wr[(row - 32) * 64 + col];
    }
    {
        int n = n0 + w;
        int c = cnt[n];
        if (c > MAXD) c = MAXD;
        const int* bucket = csr + n * MAXD;
        float acc = 0.f;
        for (int e2 = 0; e2 < c; ++e2) {
            size_t o = (size_t)bucket[e2] * 128 + lane;
            acc += b2f(ypu[o]) + b2f(yp1[o]);
        }
        float rc = (c > 0) ? (1.f / (float)c) : 0.f;
        size_t ro = (size_t)n * 128 + 64 + lane;
        Xs[w][lane] = fmaxf(acc * rc + b[lane] + b2f(ypu[ro]) + b2f(yp1[ro]), 0.f);
    }
    __syncthreads();
    const int tg = t >> 6, tc = t & 63;
    float acc2 = 0.f;
    #pragma unroll 8
    for (int k = 0; k < 64; ++k)
        acc2 = fmaf(Xs[tg][k], Ws[tc][k], acc2);
    yout[(size_t)(n0 + tg) * 64 + tc] = acc2;
}

// ---------- layer2 fused: fp32 gather + combine + GEMM ----------
__global__ __launch_bounds__(256) void layer2_fused(const float* __restrict__ yprev, const int* __restrict__ csr,
                                                    const int* __restrict__ cnt,
                                                    const float* __restrict__ b,
                                                    const float* __restrict__ Wl, const float* __restrict__ Wr,
                                                    float* __restrict__ yout) {
    __shared__ float Xs[4][33];
    __shared__ float Ws[64][33];
    const int t = threadIdx.x;
    const int w = t >> 6, lane = t & 63;
    const int n0 = blockIdx.x * 4;

    #pragma unroll
    for (int i = 0; i < 8; ++i) {
        int e2 = t + i * 256;
        int row = e2 >> 5, col = e2 & 31;
        Ws[row][col] = (row < 32) ? Wl[row * 32 + col] : Wr[(row - 32) * 32 + col];
    }
    {
        int n = n0 + w;
        int c = cnt[n];
        if (c > MAXD) c = MAXD;
        const int* bucket = csr + n * MAXD;
        int half = lane >> 5, d = lane & 31;
        float acc = 0.f;
        for (int e2 = half; e2 < c; e2 += 2)
            acc += yprev[(size_t)bucket[e2] * 64 + d];
        acc += __shfl_xor(acc, 32);
        if (lane < 32) {
            float rc = (c > 0) ? (1.f / (float)c) : 0.f;
            Xs[w][d] = fmaxf(acc * rc + b[d] + yprev[(size_t)n * 64 + 32 + d], 0.f);
        }
    }
    __syncthreads();
    const int tg = t >> 6, tc = t & 63;
    float acc2 = 0.f;
    #pragma unroll 8
    for (int k = 0; k < 32; ++k)
        acc2 = fmaf(Xs[tg][k], Ws[tc][k], acc2);
    yout[(size_t)(n0 + tg) * 64 + tc] = acc2;
}

// ---------- fin: gather + combine + collapsed MLP + log_softmax ----------
__global__ __launch_bounds__(256) void fin_fused(const float* __restrict__ y3, const int* __restrict__ csr,
                                                 const int* __restrict__ cnt,
                                                 const float* __restrict__ b3,
                                                 const float* __restrict__ Mc, const float* __restrict__ bc,
                                                 float* __restrict__ out) {
    const int t = threadIdx.x;
    const int w = t >> 6, lane = t & 63;
    const int n = blockIdx.x * 4 + w;

    int c = cnt[n];
    if (c > MAXD) c = MAXD;
    const int* bucket = csr + n * MAXD;
    int half = lane >> 5, d = lane & 31;
    float acc = 0.f;
    for (int e2 = half; e2 < c; e2 += 2)
        acc += y3[(size_t)bucket[e2] * 64 + d];
    acc += __shfl_xor(acc, 32);
    float hv = 0.f;
    if (lane < 32) {
        float rc = (c > 0) ? (1.f / (float)c) : 0.f;
        hv = fmaxf(acc * rc + b3[lane] + y3[(size_t)n * 64 + 32 + lane], 0.f);
    }
    float uv = (lane < 7) ? bc[lane] : 0.f;
    #pragma unroll 8
    for (int k = 0; k < 32; ++k) {
        float hk = __shfl(hv, k, 64);
        if (lane < 7) uv = fmaf(hk, Mc[lane * 32 + k], uv);
    }
    float m = -1e30f;
    float uc[7];
    #pragma unroll
    for (int c2 = 0; c2 < 7; ++c2) { uc[c2] = __shfl(uv, c2, 64); m = fmaxf(m, uc[c2]); }
    float s = 0.f;
    #pragma unroll
    for (int c2 = 0; c2 < 7; ++c2) s += expf(uc[c2] - m);
    float lse = m + logf(s);
    if (lane < 7) out[n * 7 + lane] = uv - lse;
}

extern "C" void kernel_launch(void* const* d_in, const int* in_sizes, int n_in,
                              void* d_out, int out_size, void* d_ws, size_t ws_size,
                              hipStream_t stream) {
    const float* x   = (const float*)d_in[0];
    const int*   eix = (const int*)d_in[1];
    const float* W1l = (const float*)d_in[2];
    const float* b1  = (const float*)d_in[3];
    const float* W1r = (const float*)d_in[4];
    const float* W2l = (const float*)d_in[5];
    const float* b2  = (const float*)d_in[6];
    const float* W2r = (const float*)d_in[7];
    const float* W3l = (const float*)d_in[8];
    const float* b3  = (const float*)d_in[9];
    const float* W3r = (const float*)d_in[10];
    const float* M1w = (const float*)d_in[11];
    const float* M1b = (const float*)d_in[12];
    const float* M2w = (const float*)d_in[13];
    const float* M2b = (const float*)d_in[14];
    float* out = (float*)d_out;

    char* w = (char*)d_ws;
    int*   cnt  = (int*)w;    w += 40960;       // zeroed each call
    int*   csr  = (int*)w;    w += (size_t)NN * MAXD * 4;
    u16*   ypu  = (u16*)w;    w += (size_t)SK1 * NN * 128 * 2;
    float* y2   = (float*)w;  w += NN * 64 * 4;
    float* y3   = (float*)w;  w += NN * 64 * 4;
    float* Mc   = (float*)w;  w += 8 * 32 * 4;
    float* bcv  = (float*)w;  w += 8 * 4;
    u16*   Wb   = (u16*)w;    w += 128 * KP * 2;

    (void)hipMemsetAsync(cnt, 0, NN * 4, stream);
    prep_kernel<<<722, 256, 0, stream>>>(eix, cnt, csr, W1l, W1r, Wb, M1w, M1b, M2w, M2b, Mc, bcv);

    {
        dim3 grid((NN + 31) / 32, 4);   // (n-tile, ky*2+ch)
        mm1_mfma<<<grid, 256, 0, stream>>>(x, Wb, ypu);
    }

    layer1_fused<<<2500, 256, 0, stream>>>(ypu, csr, cnt, b1, W2l, W2r, y2);
    layer2_fused<<<2500, 256, 0, stream>>>(y2, csr, cnt, b2, W3l, W3r, y3);
    fin_fused<<<2500, 256, 0, stream>>>(y3, csr, cnt, b3, Mc, bcv, out);
}

// Round 27
// 105.871 us; speedup vs baseline: 1.0626x; 1.0626x over previous
//
#include <hip/hip_runtime.h>

#define NN 10000
#define NE 160000
#define KD 1433
#define KP 1536    // padded K (zero-filled in Wb)
#define SK1 2      // split-K partial buffers (interleaved [n][2][128])
#define KC 768     // K per block
#define KSTEP 64   // K per LDS stage
#define NST 12     // KC/KSTEP
#define MAXD 64    // slot-CSR bucket size (P(deg>64) ~ 1e-12, clamped)

typedef unsigned short u16;
typedef __attribute__((ext_vector_type(4))) float f32x4;
typedef __attribute__((ext_vector_type(8))) short bf16x8;
typedef __attribute__((ext_vector_type(4), aligned(4))) float f32x4u;

__device__ __forceinline__ u16 f2bf(float f) {
    union { float f; unsigned u; } v; v.f = f;
    unsigned r = (v.u + 0x7FFF + ((v.u >> 16) & 1)) >> 16;
    return (u16)r;
}
__device__ __forceinline__ float b2f(u16 u) {
    union { unsigned u; float f; } v; v.u = ((unsigned)u) << 16;
    return v.f;
}

__device__ __forceinline__ void gload16(const void* g, void* l) {
    __builtin_amdgcn_global_load_lds(
        (__attribute__((address_space(1))) void*)(void*)g,
        (__attribute__((address_space(3))) void*)l, 16, 0, 0);
}

// ---------- prep: edges repack + slot-CSR scatter + degree | convw | MLP collapse ----------
__global__ __launch_bounds__(256) void prep_kernel(const int* __restrict__ e,
                                                   int* __restrict__ cnt, int* __restrict__ csr,
                                                   const float* __restrict__ Wl, const float* __restrict__ Wr,
                                                   u16* __restrict__ Wb,
                                                   const float* __restrict__ M1w, const float* __restrict__ M1b,
                                                   const float* __restrict__ M2w, const float* __restrict__ M2b,
                                                   float* __restrict__ Mc, float* __restrict__ bc) {
    const int b = blockIdx.x, t = threadIdx.x;
    if (b < 625) {
        __shared__ int nzs;
        if (t == 0) nzs = 0;
        __syncthreads();
        int i = b * 256 + t;
        int hv = (i < NE) ? e[2 * i + 1] : 0;
        if (hv) nzs = 1;   // benign race
        __syncthreads();
        if (i < NE) {
            int s, d;
            if (nzs == 0) { s = e[2 * i]; d = e[2 * (NE + i)]; }
            else          { s = e[i];     d = e[NE + i]; }
            int pos = atomicAdd(&cnt[d], 1);
            if (pos < MAXD) csr[d * MAXD + pos] = s;
        }
    } else if (b < 721) {
        int gid = (b - 625) * 256 + t;
        int r = gid / (KP / 8), k0 = (gid % (KP / 8)) * 8;
        const float* srcw = (r < 64) ? (Wl + r * KD) : (Wr + (r - 64) * KD);
        u16 u[8];
        #pragma unroll
        for (int i = 0; i < 8; ++i) {
            int k = k0 + i;
            u[i] = (k < KD) ? f2bf(srcw[k]) : (u16)0;
        }
        *(uint4*)&Wb[r * KP + k0] = *(const uint4*)u;
    } else {
        if (t < 224) {
            int c = t >> 5, d = t & 31;
            float acc = 0.f;
            for (int k = 0; k < 32; ++k)
                acc += M2w[c * 32 + k] * M1w[k * 32 + d];
            Mc[t] = acc;
        } else if (t < 232) {
            Mc[t] = 0.f;
            int c = t - 224;
            if (c < 7) {
                float acc = M2b[c];
                for (int k = 0; k < 32; ++k)
                    acc += M2w[c * 32 + k] * M1b[k];
                bc[c] = acc;
            } else bc[7] = 0.f;
        } else Mc[t] = 0.f;
    }
}

// ---------- layer-1 MFMA GEMM (R25 form): counted-vmcnt, bf16 interleaved partials ----------
__global__ __launch_bounds__(256) void mm1_mfma(const float* __restrict__ x, const u16* __restrict__ Wb,
                                                u16* __restrict__ ypu) {
    __shared__ float AT[2][2048];
    __shared__ u16  WT[2][8192];
    const int t = threadIdx.x;
    const int w = t >> 6, lane = t & 63;
    const int n0 = blockIdx.x * 32;
    const int kc0 = blockIdx.y * KC;

    const int rowinA = lane >> 4;
    const int cA = lane & 15;
    size_t aoff[2];
    #pragma unroll
    for (int ii = 0; ii < 2; ++ii) {
        int i = 2 * w + ii;
        int r = 4 * i + rowinA;
        int grow = n0 + r; if (grow >= NN) grow = NN - 1;
        int q = cA ^ (rowinA << 2) ^ (i & 3);
        aoff[ii] = (size_t)grow * KD + (size_t)kc0 + (size_t)(q * 4);
    }
    const size_t amax = (size_t)NN * KD - 4;
    const int rowinW = lane >> 3;
    const int qw = (lane & 7) ^ rowinW;
    size_t woff[4];
    #pragma unroll
    for (int jj = 0; jj < 4; ++jj) {
        int j = 4 * w + jj;
        int r = 8 * j + rowinW;
        woff[jj] = (size_t)r * KP + (size_t)kc0 + (size_t)(qw * 8);
    }

    const int fr = lane & 15, hi = lane >> 4;
    const int ar0 = (w & 1) * 16;
    const int c0w = (w >> 1) * 64;
    const int arow = ar0 + fr;
    const int apage = (arow >> 2) * 256 + (arow & 3) * 64;
    const int asw = ((arow & 3) << 2) ^ ((arow >> 2) & 3);

    f32x4 acc[4] = {};

    auto stage = [&](int s, int bb) {
        const int ko = s * KSTEP;
        #pragma unroll
        for (int ii = 0; ii < 2; ++ii) {
            size_t o = aoff[ii] + ko;
            if (o > amax) o = amax;
            gload16(x + o, &AT[bb][(2 * w + ii) * 256]);
        }
        #pragma unroll
        for (int jj = 0; jj < 4; ++jj)
            gload16(Wb + woff[jj] + ko, &WT[bb][(4 * w + jj) * 512]);
    };

    stage(0, 0);
    stage(1, 1);

    for (int s = 0; s < NST; ++s) {
        if (s + 1 < NST) {
            asm volatile("s_waitcnt vmcnt(6)" ::: "memory");
        } else {
            asm volatile("s_waitcnt vmcnt(0)" ::: "memory");
        }
        __builtin_amdgcn_sched_barrier(0);
        __builtin_amdgcn_s_barrier();
        __builtin_amdgcn_sched_barrier(0);

        const float* ab = &AT[s & 1][0];
        const u16* wbuf = &WT[s & 1][0];
        #pragma unroll
        for (int p = 0; p < 2; ++p) {
            const int q0 = p * 8 + hi * 2;
            f32x4 alo = *(const f32x4*)&ab[apage + ((q0    ) ^ asw) * 4];
            f32x4 ahi = *(const f32x4*)&ab[apage + ((q0 + 1) ^ asw) * 4];
            u16 au[8] = { f2bf(alo[0]), f2bf(alo[1]), f2bf(alo[2]), f2bf(alo[3]),
                          f2bf(ahi[0]), f2bf(ahi[1]), f2bf(ahi[2]), f2bf(ahi[3]) };
            bf16x8 af = *(const bf16x8*)au;
            #pragma unroll
            for (int f = 0; f < 4; ++f) {
                int wrow = c0w + f * 16 + fr;
                int kcw = (p * 4 + hi) ^ (wrow & 7);
                bf16x8 bfr = *(const bf16x8*)&wbuf[(wrow >> 3) * 512 + (wrow & 7) * 64 + kcw * 8];
                acc[f] = __builtin_amdgcn_mfma_f32_16x16x32_bf16(af, bfr, acc[f], 0, 0, 0);
            }
        }

        __builtin_amdgcn_sched_barrier(0);
        __builtin_amdgcn_s_barrier();
        __builtin_amdgcn_sched_barrier(0);
        if (s + 2 < NST) stage(s + 2, s & 1);
    }

    // interleaved partials: ypu[n*256 + ky*128 + col]
    u16* ypb = ypu + (size_t)blockIdx.y * 128;
    #pragma unroll
    for (int f = 0; f < 4; ++f) {
        #pragma unroll
        for (int j = 0; j < 4; ++j) {
            int n = n0 + ar0 + hi * 4 + j;
            int col = c0w + f * 16 + fr;
            if (n < NN) ypb[(size_t)n * 256 + col] = f2bf(acc[f][j]);
        }
    }
}

// ---------- layer1 fused: bf16 gather (interleaved partials) + combine + GEMM ----------
__global__ __launch_bounds__(256) void layer1_fused(const u16* __restrict__ ypu, const int* __restrict__ csr,
                                                    const int* __restrict__ cnt,
                                                    const float* __restrict__ b,
                                                    const float* __restrict__ Wl, const float* __restrict__ Wr,
                                                    float* __restrict__ yout) {
    __shared__ float Xs[4][65];
    __shared__ float Ws[64][65];
    const int t = threadIdx.x;
    const int w = t >> 6, lane = t & 63;
    const int n0 = blockIdx.x * 4;

    #pragma unroll
    for (int i = 0; i < 16; ++i) {
        int e2 = t + i * 256;
        int row = e2 >> 6, col = e2 & 63;
        Ws[row][col] = (row < 32) ? Wl[row * 64 + col] : Wr[(row - 32) * 64 + col];
    }
    {
        int n = n0 + w;
        int c = cnt[n];
        if (c > MAXD) c = MAXD;
        const int* bucket = csr + n * MAXD;
        float acc = 0.f;
        for (int e2 = 0; e2 < c; ++e2) {
            size_t o = (size_t)bucket[e2] * 256 + lane;
            acc += b2f(ypu[o]) + b2f(ypu[o + 128]);   // both partials adjacent (512B region)
        }
        float rc = (c > 0) ? (1.f / (float)c) : 0.f;
        size_t ro = (size_t)n * 256 + 64 + lane;
        Xs[w][lane] = fmaxf(acc * rc + b[lane] + b2f(ypu[ro]) + b2f(ypu[ro + 128]), 0.f);
    }
    __syncthreads();
    const int tg = t >> 6, tc = t & 63;
    float acc2 = 0.f;
    #pragma unroll 8
    for (int k = 0; k < 64; ++k)
        acc2 = fmaf(Xs[tg][k], Ws[tc][k], acc2);
    yout[(size_t)(n0 + tg) * 64 + tc] = acc2;
}

// ---------- layer2 fused: fp32 gather + combine + GEMM ----------
__global__ __launch_bounds__(256) void layer2_fused(const float* __restrict__ yprev, const int* __restrict__ csr,
                                                    const int* __restrict__ cnt,
                                                    const float* __restrict__ b,
                                                    const float* __restrict__ Wl, const float* __restrict__ Wr,
                                                    float* __restrict__ yout) {
    __shared__ float Xs[4][33];
    __shared__ float Ws[64][33];
    const int t = threadIdx.x;
    const int w = t >> 6, lane = t & 63;
    const int n0 = blockIdx.x * 4;

    #pragma unroll
    for (int i = 0; i < 8; ++i) {
        int e2 = t + i * 256;
        int row = e2 >> 5, col = e2 & 31;
        Ws[row][col] = (row < 32) ? Wl[row * 32 + col] : Wr[(row - 32) * 32 + col];
    }
    {
        int n = n0 + w;
        int c = cnt[n];
        if (c > MAXD) c = MAXD;
        const int* bucket = csr + n * MAXD;
        int half = lane >> 5, d = lane & 31;
        float acc = 0.f;
        for (int e2 = half; e2 < c; e2 += 2)
            acc += yprev[(size_t)bucket[e2] * 64 + d];
        acc += __shfl_xor(acc, 32);
        if (lane < 32) {
            float rc = (c > 0) ? (1.f / (float)c) : 0.f;
            Xs[w][d] = fmaxf(acc * rc + b[d] + yprev[(size_t)n * 64 + 32 + d], 0.f);
        }
    }
    __syncthreads();
    const int tg = t >> 6, tc = t & 63;
    float acc2 = 0.f;
    #pragma unroll 8
    for (int k = 0; k < 32; ++k)
        acc2 = fmaf(Xs[tg][k], Ws[tc][k], acc2);
    yout[(size_t)(n0 + tg) * 64 + tc] = acc2;
}

// ---------- fin: gather + combine + collapsed MLP + log_softmax ----------
__global__ __launch_bounds__(256) void fin_fused(const float* __restrict__ y3, const int* __restrict__ csr,
                                                 const int* __restrict__ cnt,
                                                 const float* __restrict__ b3,
                                                 const float* __restrict__ Mc, const float* __restrict__ bc,
                                                 float* __restrict__ out) {
    const int t = threadIdx.x;
    const int w = t >> 6, lane = t & 63;
    const int n = blockIdx.x * 4 + w;

    int c = cnt[n];
    if (c > MAXD) c = MAXD;
    const int* bucket = csr + n * MAXD;
    int half = lane >> 5, d = lane & 31;
    float acc = 0.f;
    for (int e2 = half; e2 < c; e2 += 2)
        acc += y3[(size_t)bucket[e2] * 64 + d];
    acc += __shfl_xor(acc, 32);
    float hv = 0.f;
    if (lane < 32) {
        float rc = (c > 0) ? (1.f / (float)c) : 0.f;
        hv = fmaxf(acc * rc + b3[lane] + y3[(size_t)n * 64 + 32 + lane], 0.f);
    }
    float uv = (lane < 7) ? bc[lane] : 0.f;
    #pragma unroll 8
    for (int k = 0; k < 32; ++k) {
        float hk = __shfl(hv, k, 64);
        if (lane < 7) uv = fmaf(hk, Mc[lane * 32 + k], uv);
    }
    float m = -1e30f;
    float uc[7];
    #pragma unroll
    for (int c2 = 0; c2 < 7; ++c2) { uc[c2] = __shfl(uv, c2, 64); m = fmaxf(m, uc[c2]); }
    float s = 0.f;
    #pragma unroll
    for (int c2 = 0; c2 < 7; ++c2) s += expf(uc[c2] - m);
    float lse = m + logf(s);
    if (lane < 7) out[n * 7 + lane] = uv - lse;
}

extern "C" void kernel_launch(void* const* d_in, const int* in_sizes, int n_in,
                              void* d_out, int out_size, void* d_ws, size_t ws_size,
                              hipStream_t stream) {
    const float* x   = (const float*)d_in[0];
    const int*   eix = (const int*)d_in[1];
    const float* W1l = (const float*)d_in[2];
    const float* b1  = (const float*)d_in[3];
    const float* W1r = (const float*)d_in[4];
    const float* W2l = (const float*)d_in[5];
    const float* b2  = (const float*)d_in[6];
    const float* W2r = (const float*)d_in[7];
    const float* W3l = (const float*)d_in[8];
    const float* b3  = (const float*)d_in[9];
    const float* W3r = (const float*)d_in[10];
    const float* M1w = (const float*)d_in[11];
    const float* M1b = (const float*)d_in[12];
    const float* M2w = (const float*)d_in[13];
    const float* M2b = (const float*)d_in[14];
    float* out = (float*)d_out;

    char* w = (char*)d_ws;
    int*   cnt  = (int*)w;    w += 40960;       // zeroed each call
    int*   csr  = (int*)w;    w += (size_t)NN * MAXD * 4;
    u16*   ypu  = (u16*)w;    w += (size_t)NN * 256 * 2;   // interleaved [n][2][128]
    float* y2   = (float*)w;  w += NN * 64 * 4;
    float* y3   = (float*)w;  w += NN * 64 * 4;
    float* Mc   = (float*)w;  w += 8 * 32 * 4;
    float* bcv  = (float*)w;  w += 8 * 4;
    u16*   Wb   = (u16*)w;    w += 128 * KP * 2;

    (void)hipMemsetAsync(cnt, 0, NN * 4, stream);
    prep_kernel<<<722, 256, 0, stream>>>(eix, cnt, csr, W1l, W1r, Wb, M1w, M1b, M2w, M2b, Mc, bcv);

    {
        dim3 grid((NN + 31) / 32, SK1);
        mm1_mfma<<<grid, 256, 0, stream>>>(x, Wb, ypu);
    }

    layer1_fused<<<2500, 256, 0, stream>>>(ypu, csr, cnt, b1, W2l, W2r, y2);
    layer2_fused<<<2500, 256, 0, stream>>>(y2, csr, cnt, b2, W3l, W3r, y3);
    fin_fused<<<2500, 256, 0, stream>>>(y3, csr, cnt, b3, Mc, bcv, out);
}